// Round 2
// baseline (100.350 us; speedup 1.0000x reference)
//
#include <hip/hip_runtime.h>
#include <math.h>

// Fused HybridEstimatorQNN forward:
//   q = sin(x0) * sin(x1 + w)
//   h1 = tanh([x0,x1,q] @ W1 + b1)   (3->8)
//   h2 = tanh(h1 @ W2 + b2)          (8->4)
//   out = h2 @ W3 + b3               (4->1)
//
// tanh(x) = 2r - 1, r = rcp(1 + exp2(-2*log2e*x)).  The "2r-1" affine is
// folded into the NEXT layer's weights/biases (W' = 2W, b' = b - sum(W)),
// so each tanh costs only {mul, add, exp2, rcp} and r feeds forward raw.
//
// One pass over inputs, no intermediates in HBM. 4 elements/thread:
// 2x float4 loads, 1x float4 store.

#define NEG2LOG2E -2.8853900817779268f
#define INV2PI     0.15915494309189535f

__device__ __forceinline__ float sigm2(float x) {
    // r = 1/(1 + e^{-2x}) = (tanh(x)+1)/2 ; saturates correctly at +-inf.
    float t = __builtin_amdgcn_exp2f(x * NEG2LOG2E);
    return __builtin_amdgcn_rcpf(1.0f + t);
}

__global__ __launch_bounds__(256) void qnn_fused_kernel(
    const float* __restrict__ in,   // [n,2]
    const float* __restrict__ W1,   // [3,8]
    const float* __restrict__ b1,   // [8]
    const float* __restrict__ W2,   // [8,4]
    const float* __restrict__ b2,   // [4]
    const float* __restrict__ W3,   // [4,1]
    const float* __restrict__ b3,   // [1]
    const float* __restrict__ wq,   // [1]
    float* __restrict__ out,        // [n]
    int n)
{
    // ---- hoist + pre-fold params (uniform addresses -> SGPRs) ----
    const float wC = wq[0] * INV2PI;        // folded into sin argument

    float w1[3][8];
#pragma unroll
    for (int i = 0; i < 3; ++i)
#pragma unroll
        for (int j = 0; j < 8; ++j) w1[i][j] = W1[i * 8 + j];
    float bb1[8];
#pragma unroll
    for (int j = 0; j < 8; ++j) bb1[j] = b1[j];

    // layer 2 folded: acc = (b2_j - sum_i W2_ij) + sum_i r1_i * (2 W2_ij)
    float w2d[8][4];
    float bb2p[4];
#pragma unroll
    for (int j = 0; j < 4; ++j) {
        float s = 0.0f;
#pragma unroll
        for (int i = 0; i < 8; ++i) {
            float v = W2[i * 4 + j];
            w2d[i][j] = 2.0f * v;
            s += v;
        }
        bb2p[j] = b2[j] - s;
    }

    // layer 3 folded: out = (b3 - sum_i W3_i) + sum_i r2_i * (2 W3_i)
    float w3d[4];
    float s3 = 0.0f;
#pragma unroll
    for (int i = 0; i < 4; ++i) { float v = W3[i]; w3d[i] = 2.0f * v; s3 += v; }
    const float bb3p = b3[0] - s3;

    auto forward = [&](float x0, float x1) -> float {
        float q = __builtin_amdgcn_sinf(x0 * INV2PI)
                * __builtin_amdgcn_sinf(fmaf(x1, INV2PI, wC));
        float r1[8];
#pragma unroll
        for (int j = 0; j < 8; ++j) {
            float acc = fmaf(x0, w1[0][j],
                        fmaf(x1, w1[1][j],
                        fmaf(q,  w1[2][j], bb1[j])));
            r1[j] = sigm2(acc);
        }
        float r2[4];
#pragma unroll
        for (int j = 0; j < 4; ++j) {
            float acc = bb2p[j];
#pragma unroll
            for (int i = 0; i < 8; ++i) acc = fmaf(r1[i], w2d[i][j], acc);
            r2[j] = sigm2(acc);
        }
        float o = bb3p;
#pragma unroll
        for (int i = 0; i < 4; ++i) o = fmaf(r2[i], w3d[i], o);
        return o;
    };

    const int base = (blockIdx.x * blockDim.x + threadIdx.x) * 4;
    if (base + 3 < n) {
        // fast path: vector loads/stores (32B-aligned input, 16B-aligned output)
        const float4 p0 = *reinterpret_cast<const float4*>(in + 2 * base);
        const float4 p1 = *reinterpret_cast<const float4*>(in + 2 * base + 4);
        float4 o;
        o.x = forward(p0.x, p0.y);
        o.y = forward(p0.z, p0.w);
        o.z = forward(p1.x, p1.y);
        o.w = forward(p1.z, p1.w);
        *reinterpret_cast<float4*>(out + base) = o;
    } else {
        // tail
        for (int e = 0; e < 4; ++e) {
            int i = base + e;
            if (i < n) out[i] = forward(in[2 * i], in[2 * i + 1]);
        }
    }
}

extern "C" void kernel_launch(void* const* d_in, const int* in_sizes, int n_in,
                              void* d_out, int out_size, void* d_ws, size_t ws_size,
                              hipStream_t stream) {
    const float* in = (const float*)d_in[0];
    const float* W1 = (const float*)d_in[1];
    const float* b1 = (const float*)d_in[2];
    const float* W2 = (const float*)d_in[3];
    const float* b2 = (const float*)d_in[4];
    const float* W3 = (const float*)d_in[5];
    const float* b3 = (const float*)d_in[6];
    const float* wq = (const float*)d_in[7];
    float* out = (float*)d_out;

    const int n = out_size;                 // B rows
    const int threads = 256;
    const int elems_per_block = threads * 4;
    const int blocks = (n + elems_per_block - 1) / elems_per_block;

    hipLaunchKernelGGL(qnn_fused_kernel, dim3(blocks), dim3(threads), 0, stream,
                       in, W1, b1, W2, b2, W3, b3, wq, out, n);
}